// Round 4
// baseline (3260.513 us; speedup 1.0000x reference)
//
#include <hip/hip_runtime.h>
#include <math.h>

#define NA      128
#define NBATCH  2048
#define NTHR    256     // R11: 256-thr blocks -> 8 blocks/CU, ONE dispatch round
#define NIT     300
#define NBIS    40      // full 40: R7 showed NBIS=24 -> absmax 8e-3 (4e4x amplification of tau noise)
#define LRC     0.02f
#define EPSC    1e-8f

// ---- wave64 cross-lane reductions via DPP (VALU pipe, no LDS traffic) ----
// The DPP tree ORDER is part of the fp contract (absmax dice): never change it.
template <int CTRL>
__device__ __forceinline__ float dpp_sum_step(float x) {
  int s = __builtin_amdgcn_update_dpp(0, __float_as_int(x), CTRL, 0xF, 0xF, true);
  return x + __int_as_float(s);
}
__device__ __forceinline__ float wave_sum64(float x) {
  x = dpp_sum_step<0x111>(x);
  x = dpp_sum_step<0x112>(x);
  x = dpp_sum_step<0x114>(x);
  x = dpp_sum_step<0x118>(x);
  x = dpp_sum_step<0x142>(x);
  x = dpp_sum_step<0x143>(x);
  return x;  // total in lane 63
}
template <int CTRL>
__device__ __forceinline__ float dpp_mov_self(float x) {
  int s = __builtin_amdgcn_update_dpp(__float_as_int(x), __float_as_int(x), CTRL, 0xF, 0xF, false);
  return __int_as_float(s);
}
__device__ __forceinline__ float wave_min64(float x) {
  x = fminf(x, dpp_mov_self<0x111>(x));
  x = fminf(x, dpp_mov_self<0x112>(x));
  x = fminf(x, dpp_mov_self<0x114>(x));
  x = fminf(x, dpp_mov_self<0x118>(x));
  x = fminf(x, dpp_mov_self<0x142>(x));
  x = fminf(x, dpp_mov_self<0x143>(x));
  return x;  // min in lane 63
}
__device__ __forceinline__ float wave_max64(float x) {
  x = fmaxf(x, dpp_mov_self<0x111>(x));
  x = fmaxf(x, dpp_mov_self<0x112>(x));
  x = fmaxf(x, dpp_mov_self<0x114>(x));
  x = fmaxf(x, dpp_mov_self<0x118>(x));
  x = fmaxf(x, dpp_mov_self<0x142>(x));
  x = fmaxf(x, dpp_mov_self<0x143>(x));
  return x;  // max in lane 63
}
__device__ __forceinline__ float bcast63(float x) {
  return __int_as_float(__builtin_amdgcn_readlane(__float_as_int(x), 63));
}
__device__ __forceinline__ float clip1(float x) {
  return __builtin_amdgcn_fmed3f(x, -1.0f, 1.0f);  // c = MAX_WEIGHT = 1
}

// R11 (this round): CONCURRENCY fix, fp arithmetic bit-identical to the
// 2685us baseline.
//  Evidence: VALUBusy ~49% at occupancy 88%; total VALU issue work is only
//  ~2600 SIMD-cy/CU/iter yet wall is ~2x that; 512-thr blocks give 4
//  blocks/CU -> 2048 blocks need TWO sequential dispatch rounds, and each
//  block's phase structure (all-wave matvec -> 2-wave reduce -> 1-wave
//  bisect) parks most waves at barriers with too few other blocks to fill
//  the stall cycles. R1/R3 showed the bisect chain itself can't be sped up
//  per-wave and isn't SIMD-placement-bound.
//  Fix: 256-thr blocks. Each thread computes TWO quarter-rows (q, q+2) with
//  the identical per-quarter fp sequence, writing the same part[r+128q]
//  slots -> Aw combine / reductions / gradient / bisection bit-identical.
//  8 blocks/CU: ONE dispatch round (was 2) and 8 independent chains+matvecs
//  per CU to fill each other's bubbles.
//  (A-tile note: allocator remats A to per-iter cache loads + x gm anyway
//  (VGPR=32, R9 spill fiasco) -> in-loop load+mul IS the baseline codegen.)
__global__ __launch_bounds__(NTHR)
void markowitz_kernel(
    const float* __restrict__ rets,
    const float* __restrict__ covmat,
    const float* __restrict__ gamma,
    const float* __restrict__ alpha,
    float* __restrict__ out)
{
  const int b    = blockIdx.x;
  const int tid  = threadIdx.x;     // 0..255
  const int r    = tid & (NA - 1);  // row 0..127
  const int q0   = tid >> 7;        // first quarter: 0 or 1 (also handles q0+2)
  const int lane = tid & 63;
  const int wv   = tid >> 6;        // wave 0..3
  const int chain_wv = ((b >> 8) ^ b) & 3;  // spread chains across co-resident blocks

  __shared__ __align__(16) float ws[NA];      // current weights
  __shared__ __align__(16) float vs[NA];      // pre-projection vector
  __shared__ __align__(16) float part[4 * NA]; // quarter-row partials, part[r + 128q]
  __shared__ float pp[4];                      // wAw, ww per reduce-wave 0/1

  const float gm = gamma[b];
  const float* Arow = covmat + (size_t)b * NA * NA + (size_t)r * NA + (size_t)q0 * 32;
  const float4* Aq0 = reinterpret_cast<const float4*>(Arow);        // quarter q0
  const float4* Aq1 = reinterpret_cast<const float4*>(Arow + 64);   // quarter q0+2
  const float av = fabsf(alpha[b]);
  float r_c = 0.0f;
  if (tid < NA) { r_c = rets[b * NA + tid]; ws[tid] = 1.0f / NA; }
  __syncthreads();

#pragma unroll 1
  for (int it = 0; it < NIT; ++it) {
    // ---- 1. two quarter-row dots per thread (A streamed from L1/L2,
    //         gm folded per element exactly as the baseline's staging did;
    //         w via wave-uniform LDS broadcast) ----
    const float4* w40 = reinterpret_cast<const float4*>(ws) + q0 * 8;
    const float4* w41 = w40 + 16;  // quarter q0+2
    float4 acc0 = make_float4(0.f, 0.f, 0.f, 0.f);
    float4 acc1 = make_float4(0.f, 0.f, 0.f, 0.f);
#pragma unroll
    for (int k = 0; k < 8; ++k) {
      float4 t0 = Aq0[k];
      float4 wk0 = w40[k];
      acc0.x = fmaf(t0.x * gm, wk0.x, acc0.x);
      acc0.y = fmaf(t0.y * gm, wk0.y, acc0.y);
      acc0.z = fmaf(t0.z * gm, wk0.z, acc0.z);
      acc0.w = fmaf(t0.w * gm, wk0.w, acc0.w);
      float4 t1 = Aq1[k];
      float4 wk1 = w41[k];
      acc1.x = fmaf(t1.x * gm, wk1.x, acc1.x);
      acc1.y = fmaf(t1.y * gm, wk1.y, acc1.y);
      acc1.z = fmaf(t1.z * gm, wk1.z, acc1.z);
      acc1.w = fmaf(t1.w * gm, wk1.w, acc1.w);
    }
    part[tid]       = (acc0.x + acc0.y) + (acc0.z + acc0.w);  // slot r + 128*q0
    part[tid + 256] = (acc1.x + acc1.y) + (acc1.z + acc1.w);  // slot r + 128*(q0+2)
    __syncthreads();

    // ---- 2. combine quarters; wAw / ww reductions (waves 0,1) ----
    float Aw = 0.f, w_c = 0.f;
    if (tid < NA) {
      Aw  = (part[tid] + part[tid + NA]) + (part[tid + 2 * NA] + part[tid + 3 * NA]);
      w_c = ws[tid];
      float p1 = wave_sum64(w_c * Aw);
      float p2 = wave_sum64(w_c * w_c);
      if (lane == 63) { pp[wv * 2 + 0] = p1; pp[wv * 2 + 1] = p2; }
    }
    __syncthreads();

    // ---- 3. gradient step -> v (waves 0,1) ----
    if (tid < NA) {
      const float risk = sqrtf(pp[0] + pp[2] + EPSC);
      const float nrm  = sqrtf(pp[1] + pp[3] + EPSC);
      const float g    = r_c - Aw / risk - av * (w_c / nrm);
      vs[tid] = w_c + LRC * g;
    }
    __syncthreads();

    // ---- 4. bisection + projection on the chain wave only (serial, NBIS=40) ----
    if (wv == chain_wv) {
      float v0 = vs[lane];
      float v1 = vs[lane + 64];
      float mn = bcast63(wave_min64(fminf(v0, v1)));
      float mx = bcast63(wave_max64(fmaxf(v0, v1)));
      float lo = mn - 2.0f;   // min(v) - c - 1
      float hi = mx + 1.0f;   // max(v) + c
#pragma unroll 1
      for (int rr = 0; rr < NBIS; ++rr) {
        const float mid = 0.5f * (lo + hi);
        float s = wave_sum64(clip1(v0 - mid) + clip1(v1 - mid));
        const float st = bcast63(s);
        const bool big = st > 1.0f;
        lo = big ? mid : lo;
        hi = big ? hi : mid;
      }
      const float tau = 0.5f * (lo + hi);
      ws[lane]      = clip1(v0 - tau);
      ws[lane + 64] = clip1(v1 - tau);
    }
    __syncthreads();
  }

  if (tid < NA) out[b * NA + tid] = ws[tid];
}

extern "C" void kernel_launch(void* const* d_in, const int* in_sizes, int n_in,
                              void* d_out, int out_size, void* d_ws, size_t ws_size,
                              hipStream_t stream) {
  const float* rets   = (const float*)d_in[0];
  const float* covmat = (const float*)d_in[1];
  const float* gamma  = (const float*)d_in[2];
  const float* alpha  = (const float*)d_in[3];
  float* out = (float*)d_out;

  hipLaunchKernelGGL(markowitz_kernel, dim3(NBATCH), dim3(NTHR), 0, stream,
                     rets, covmat, gamma, alpha, out);
}